// Round 1
// baseline (306.316 us; speedup 1.0000x reference)
//
#include <hip/hip_runtime.h>

#define B_ 4
#define N_ 4096
#define D_ 64

typedef __bf16 bf16_t;
typedef bf16_t bf16x8 __attribute__((ext_vector_type(8)));
typedef float f32x16 __attribute__((ext_vector_type(16)));

// exp2 via v_exp_f32 (inputs are pre-scaled into log2 domain)
#if __has_builtin(__builtin_amdgcn_exp2f)
#define EXP2F __builtin_amdgcn_exp2f
#else
#define EXP2F exp2f
#endif

// sqrt(log2(e)): scaling both MFMA operands by this puts S directly in
// log2 domain, so the softmax epilogue is sub+exp2 (no per-element mul).
#define SQRT_LOG2E 1.2011224087864498f

// Kernel 1: fp32 -> bf16 conversion (pre-scaled by sqrt(log2e)) + per-row
// scaled squared norms (softmax stabilizer, already in log2 domain).
__global__ void conv_norm_kernel(const float* __restrict__ X,
                                 bf16_t* __restrict__ Xb,
                                 float* __restrict__ norms) {
    int row = blockIdx.x * 4 + (threadIdx.x >> 6);
    int d   = threadIdx.x & 63;
    size_t idx = (size_t)row * D_ + d;
    float x = X[idx] * SQRT_LOG2E;
    Xb[idx] = (bf16_t)x;
    float sq = x * x;
    #pragma unroll
    for (int off = 32; off; off >>= 1) sq += __shfl_xor(sq, off);
    if (d == 0) norms[row] = sq;
}

// Compute one 32x32 S-tile (K=64) with 4 MFMAs. B-frags straight from global
// (L2-resident: X_b is only 512 KB bf16 per batch).
__device__ __forceinline__ f32x16 tile_mm(const bf16_t* __restrict__ brow,
                                          bf16x8 a0, bf16x8 a1,
                                          bf16x8 a2, bf16x8 a3) {
    bf16x8 b0 = *(const bf16x8*)(brow);
    bf16x8 b1 = *(const bf16x8*)(brow + 16);
    bf16x8 b2 = *(const bf16x8*)(brow + 32);
    bf16x8 b3 = *(const bf16x8*)(brow + 48);
    f32x16 acc;
    #pragma unroll
    for (int i = 0; i < 16; ++i) acc[i] = 0.0f;
    acc = __builtin_amdgcn_mfma_f32_32x32x16_bf16(a0, b0, acc, 0, 0, 0);
    acc = __builtin_amdgcn_mfma_f32_32x32x16_bf16(a1, b1, acc, 0, 0, 0);
    acc = __builtin_amdgcn_mfma_f32_32x32x16_bf16(a2, b2, acc, 0, 0, 0);
    acc = __builtin_amdgcn_mfma_f32_32x32x16_bf16(a3, b3, acc, 0, 0, 0);
    return acc;
}

// Kernel 2: each block owns 32 rows of one batch; 8 waves, each wave owns a
// 32-col strip of a 256-col tile (16 tiles/pass). 512 threads -> 16 waves/CU
// = 4 waves/SIMD for latency hiding (was 2). Pass 1: row sums of
// exp2(s2 - m2). Pass 2: recompute S, write exp2(s2 - lse2) non-temporally.
__global__ __launch_bounds__(512, 4) void softmax_xxt_kernel(
        const bf16_t* __restrict__ Xb,
        const float* __restrict__ norms,
        float* __restrict__ Out) {
    const int tid  = threadIdx.x;
    const int wave = tid >> 6;                 // 0..7
    const int lane = tid & 63;
    const int b    = blockIdx.x >> 7;          // 128 row-strips per batch
    const int rowbase = (blockIdx.x & 127) * 32;

    const bf16_t* Xbb = Xb + (size_t)b * N_ * D_;
    const int mcol = lane & 31;
    const int half = lane >> 5;

    // A fragments: A[m=lane&31][k=(lane>>5)*8+j], kbase = 0,16,32,48
    const bf16_t* arow = Xbb + (size_t)(rowbase + mcol) * D_ + half * 8;
    const bf16x8 a0 = *(const bf16x8*)(arow);
    const bf16x8 a1 = *(const bf16x8*)(arow + 16);
    const bf16x8 a2 = *(const bf16x8*)(arow + 32);
    const bf16x8 a3 = *(const bf16x8*)(arow + 48);

    // Stabilizer m2 (log2 domain) for the 16 rows this lane's acc regs map to:
    // row = (reg&3) + 8*(reg>>2) + 4*(lane>>5)   [measured m74/m101 C-layout]
    float lse[16];
    {
        const float* nb = norms + b * N_ + rowbase;
        #pragma unroll
        for (int r = 0; r < 16; ++r) {
            int row = (r & 3) + 8 * (r >> 2) + 4 * half;
            lse[r] = nb[row];
        }
    }

    __shared__ float partials[8][32];

    // ---------------- pass 1: denominators ----------------
    float sums[16];
    #pragma unroll
    for (int r = 0; r < 16; ++r) sums[r] = 0.0f;

    for (int t = 0; t < N_ / 256; ++t) {
        const int c0 = t * 256 + wave * 32;   // wave-private 32-col strip
        const bf16_t* brow = Xbb + (size_t)(c0 + mcol) * D_ + half * 8;
        f32x16 acc = tile_mm(brow, a0, a1, a2, a3);
        #pragma unroll
        for (int r = 0; r < 16; ++r) sums[r] += EXP2F(acc[r] - lse[r]);
    }

    // reduce over the 32 lanes (cols) of each half-wave
    #pragma unroll
    for (int r = 0; r < 16; ++r) {
        float s = sums[r];
        s += __shfl_xor(s, 1);
        s += __shfl_xor(s, 2);
        s += __shfl_xor(s, 4);
        s += __shfl_xor(s, 8);
        s += __shfl_xor(s, 16);
        sums[r] = s;
    }

    // cross-wave combine (each wave covered a different col span)
    if (mcol == 0) {
        #pragma unroll
        for (int r = 0; r < 16; ++r) {
            int row = (r & 3) + 8 * (r >> 2) + 4 * half;
            partials[wave][row] = sums[r];
        }
    }
    __syncthreads();

    #pragma unroll
    for (int r = 0; r < 16; ++r) {
        int row = (r & 3) + 8 * (r >> 2) + 4 * half;
        float tot = partials[0][row] + partials[1][row] +
                    partials[2][row] + partials[3][row] +
                    partials[4][row] + partials[5][row] +
                    partials[6][row] + partials[7][row];
        lse[r] += __log2f(tot);   // lse2 = m2 + log2(sum exp2(s2-m2))
    }

    // ---------------- pass 2: recompute + write ----------------
    float* outb = Out + (size_t)b * N_ * N_;
    for (int t = 0; t < N_ / 256; ++t) {
        const int c0 = t * 256 + wave * 32;
        const bf16_t* brow = Xbb + (size_t)(c0 + mcol) * D_ + half * 8;
        f32x16 acc = tile_mm(brow, a0, a1, a2, a3);
        #pragma unroll
        for (int r = 0; r < 16; ++r) {
            int row = rowbase + (r & 3) + 8 * (r >> 2) + 4 * half;
            float p = EXP2F(acc[r] - lse[r]);
            // streaming 268 MB: keep it from evicting L2-resident X_b
            __builtin_nontemporal_store(p, &outb[(size_t)row * N_ + (c0 + mcol)]);
        }
    }
}

extern "C" void kernel_launch(void* const* d_in, const int* in_sizes, int n_in,
                              void* d_out, int out_size, void* d_ws, size_t ws_size,
                              hipStream_t stream) {
    const float* X = (const float*)d_in[0];
    float* Out     = (float*)d_out;

    bf16_t* Xb   = (bf16_t*)d_ws;                                   // 2 MB
    float*  norms = (float*)((char*)d_ws + (size_t)B_ * N_ * D_ * sizeof(bf16_t)); // 64 KB

    conv_norm_kernel<<<(B_ * N_) / 4, 256, 0, stream>>>(X, Xb, norms);
    softmax_xxt_kernel<<<(B_ * N_) / 32, 512, 0, stream>>>(Xb, norms, Out);
}

// Round 2
// 295.874 us; speedup vs baseline: 1.0353x; 1.0353x over previous
//
#include <hip/hip_runtime.h>

#define B_ 4
#define N_ 4096
#define D_ 64

typedef __bf16 bf16_t;
typedef bf16_t bf16x8 __attribute__((ext_vector_type(8)));
typedef float f32x16 __attribute__((ext_vector_type(16)));

// exp2 via v_exp_f32 (inputs are pre-scaled into log2 domain)
#if __has_builtin(__builtin_amdgcn_exp2f)
#define EXP2F __builtin_amdgcn_exp2f
#else
#define EXP2F exp2f
#endif

// sqrt(log2(e)): scaling both MFMA operands by this puts S directly in
// log2 domain, so the softmax epilogue is sub+exp2 (no per-element mul).
#define SQRT_LOG2E 1.2011224087864498f

// Kernel 1: fp32 -> bf16 (scaled) + per-row norms + PACK into MFMA fragment
// order. Packed layout: P[g][i][lane][j] = X[g*32 + (lane&31)]
// [(lane>>5)*8 + i*16 + j]  -- the exact order a wave's lanes consume
// fragment i of row-group g. A wave-load of one fragment is then a fully
// contiguous 1 KB (8 cachelines), vs 32 scattered lines from row-major X.
__global__ void conv_pack_kernel(const float* __restrict__ X,
                                 bf16_t* __restrict__ Xp,
                                 float* __restrict__ norms) {
    const int g    = blockIdx.x * 4 + (threadIdx.x >> 6); // row-group (32 rows)
    const int lane = threadIdx.x & 63;
    const int mcol = lane & 31;
    const int half = lane >> 5;
    const int row  = g * 32 + mcol;                       // global row in [0, B*N)

    const float* xr = X + (size_t)row * D_ + half * 8;
    float sq = 0.0f;
    #pragma unroll
    for (int i = 0; i < 4; ++i) {
        float4 u0 = *(const float4*)(xr + i * 16);
        float4 u1 = *(const float4*)(xr + i * 16 + 4);
        float v[8] = {u0.x, u0.y, u0.z, u0.w, u1.x, u1.y, u1.z, u1.w};
        bf16x8 f;
        #pragma unroll
        for (int j = 0; j < 8; ++j) {
            float x = v[j] * SQRT_LOG2E;
            sq += x * x;
            f[j] = (bf16_t)x;
        }
        *(bf16x8*)(Xp + ((size_t)(g * 4 + i) * 64 + lane) * 8) = f;
    }
    sq += __shfl_xor(sq, 32);   // combine the two k-halves of the row
    if (half == 0) norms[row] = sq;
}

// Compute one 32x32 S-tile (K=64) with 4 MFMAs from packed fragments.
// bp points at this col-group's packed block; frag i is at +i*512 elements.
__device__ __forceinline__ f32x16 tile_mm(const bf16_t* __restrict__ bp,
                                          bf16x8 a0, bf16x8 a1,
                                          bf16x8 a2, bf16x8 a3) {
    bf16x8 b0 = *(const bf16x8*)(bp);
    bf16x8 b1 = *(const bf16x8*)(bp + 512);
    bf16x8 b2 = *(const bf16x8*)(bp + 1024);
    bf16x8 b3 = *(const bf16x8*)(bp + 1536);
    f32x16 acc;
    #pragma unroll
    for (int i = 0; i < 16; ++i) acc[i] = 0.0f;
    acc = __builtin_amdgcn_mfma_f32_32x32x16_bf16(a0, b0, acc, 0, 0, 0);
    acc = __builtin_amdgcn_mfma_f32_32x32x16_bf16(a1, b1, acc, 0, 0, 0);
    acc = __builtin_amdgcn_mfma_f32_32x32x16_bf16(a2, b2, acc, 0, 0, 0);
    acc = __builtin_amdgcn_mfma_f32_32x32x16_bf16(a3, b3, acc, 0, 0, 0);
    return acc;
}

// Kernel 2: each block owns 32 rows of one batch; 8 waves, each wave owns a
// 32-col strip of a 256-col tile (16 tiles/pass). All fragment loads are
// contiguous 1 KB wave-loads from the packed panel (L2-resident, 512 KB/batch).
__global__ __launch_bounds__(512, 4) void softmax_xxt_kernel(
        const bf16_t* __restrict__ Xp,
        const float* __restrict__ norms,
        float* __restrict__ Out) {
    const int tid  = threadIdx.x;
    const int wave = tid >> 6;                 // 0..7
    const int lane = tid & 63;
    const int b    = blockIdx.x >> 7;          // 128 row-strips per batch
    const int ga   = blockIdx.x & 127;         // row-group within batch
    const int rowbase = ga * 32;

    const bf16_t* Pb = Xp + (size_t)b * N_ * D_;   // packed panel for batch
    const int mcol = lane & 31;
    const int half = lane >> 5;

    // A fragments: packed group ga, frag i at + i*512 elements
    const bf16_t* ap = Pb + (size_t)ga * 2048 + (size_t)lane * 8;
    const bf16x8 a0 = *(const bf16x8*)(ap);
    const bf16x8 a1 = *(const bf16x8*)(ap + 512);
    const bf16x8 a2 = *(const bf16x8*)(ap + 1024);
    const bf16x8 a3 = *(const bf16x8*)(ap + 1536);

    // Stabilizer m2 (log2 domain) for the 16 rows this lane's acc regs map to:
    // row = (reg&3) + 8*(reg>>2) + 4*(lane>>5)   [measured m74/m101 C-layout]
    float lse[16];
    {
        const float* nb = norms + b * N_ + rowbase;
        #pragma unroll
        for (int r = 0; r < 16; ++r) {
            int row = (r & 3) + 8 * (r >> 2) + 4 * half;
            lse[r] = nb[row];
        }
    }

    __shared__ float partials[8][32];

    // ---------------- pass 1: denominators ----------------
    float sums[16];
    #pragma unroll
    for (int r = 0; r < 16; ++r) sums[r] = 0.0f;

    for (int t = 0; t < N_ / 256; ++t) {
        const int gc = t * 8 + wave;          // wave-private col-group
        const bf16_t* bp = Pb + (size_t)gc * 2048 + (size_t)lane * 8;
        f32x16 acc = tile_mm(bp, a0, a1, a2, a3);
        #pragma unroll
        for (int r = 0; r < 16; ++r) sums[r] += EXP2F(acc[r] - lse[r]);
    }

    // reduce over the 32 lanes (cols) of each half-wave
    #pragma unroll
    for (int r = 0; r < 16; ++r) {
        float s = sums[r];
        s += __shfl_xor(s, 1);
        s += __shfl_xor(s, 2);
        s += __shfl_xor(s, 4);
        s += __shfl_xor(s, 8);
        s += __shfl_xor(s, 16);
        sums[r] = s;
    }

    // cross-wave combine (each wave covered a different col span)
    if (mcol == 0) {
        #pragma unroll
        for (int r = 0; r < 16; ++r) {
            int row = (r & 3) + 8 * (r >> 2) + 4 * half;
            partials[wave][row] = sums[r];
        }
    }
    __syncthreads();

    #pragma unroll
    for (int r = 0; r < 16; ++r) {
        int row = (r & 3) + 8 * (r >> 2) + 4 * half;
        float tot = partials[0][row] + partials[1][row] +
                    partials[2][row] + partials[3][row] +
                    partials[4][row] + partials[5][row] +
                    partials[6][row] + partials[7][row];
        lse[r] += __log2f(tot);   // lse2 = m2 + log2(sum exp2(s2-m2))
    }

    // ---------------- pass 2: recompute + write ----------------
    float* outb = Out + (size_t)b * N_ * N_;
    for (int t = 0; t < N_ / 256; ++t) {
        const int gc = t * 8 + wave;
        const int c0 = gc * 32;
        const bf16_t* bp = Pb + (size_t)gc * 2048 + (size_t)lane * 8;
        f32x16 acc = tile_mm(bp, a0, a1, a2, a3);
        #pragma unroll
        for (int r = 0; r < 16; ++r) {
            int row = rowbase + (r & 3) + 8 * (r >> 2) + 4 * half;
            float p = EXP2F(acc[r] - lse[r]);
            // streaming 268 MB: keep it from evicting L2-resident packed panel
            __builtin_nontemporal_store(p, &outb[(size_t)row * N_ + (c0 + mcol)]);
        }
    }
}

extern "C" void kernel_launch(void* const* d_in, const int* in_sizes, int n_in,
                              void* d_out, int out_size, void* d_ws, size_t ws_size,
                              hipStream_t stream) {
    const float* X = (const float*)d_in[0];
    float* Out     = (float*)d_out;

    bf16_t* Xp    = (bf16_t*)d_ws;                                   // 2 MB packed
    float*  norms = (float*)((char*)d_ws + (size_t)B_ * N_ * D_ * sizeof(bf16_t)); // 64 KB

    conv_pack_kernel<<<(B_ * N_) / 128, 256, 0, stream>>>(X, Xp, norms);
    softmax_xxt_kernel<<<(B_ * N_) / 32, 512, 0, stream>>>(Xp, norms, Out);
}

// Round 3
// 278.048 us; speedup vs baseline: 1.1017x; 1.0641x over previous
//
#include <hip/hip_runtime.h>

#define B_ 4
#define N_ 4096
#define D_ 64

typedef __bf16 bf16_t;
typedef bf16_t bf16x8 __attribute__((ext_vector_type(8)));
typedef float f32x16 __attribute__((ext_vector_type(16)));

// exp2 via v_exp_f32 (inputs are pre-scaled into log2 domain)
#if __has_builtin(__builtin_amdgcn_exp2f)
#define EXP2F __builtin_amdgcn_exp2f
#else
#define EXP2F exp2f
#endif

// sqrt(log2(e)): scaling both MFMA operands by this puts S directly in
// log2 domain, so the softmax epilogue is sub+exp2 (no per-element mul).
#define SQRT_LOG2E 1.2011224087864498f

// Kernel 1: fp32 -> bf16 (scaled) + per-row norms + PACK into MFMA fragment
// order. Packed layout: P[g][i][lane][j] = X[g*32 + (lane&31)]
// [(lane>>5)*8 + i*16 + j]  -- the exact order a wave's lanes consume
// fragment i of row-group g. A wave-load of one fragment is a contiguous 1 KB.
__global__ void conv_pack_kernel(const float* __restrict__ X,
                                 bf16_t* __restrict__ Xp,
                                 float* __restrict__ norms) {
    const int g    = blockIdx.x * 4 + (threadIdx.x >> 6); // row-group (32 rows)
    const int lane = threadIdx.x & 63;
    const int mcol = lane & 31;
    const int half = lane >> 5;
    const int row  = g * 32 + mcol;                       // global row in [0, B*N)

    const float* xr = X + (size_t)row * D_ + half * 8;
    float sq = 0.0f;
    #pragma unroll
    for (int i = 0; i < 4; ++i) {
        float4 u0 = *(const float4*)(xr + i * 16);
        float4 u1 = *(const float4*)(xr + i * 16 + 4);
        float v[8] = {u0.x, u0.y, u0.z, u0.w, u1.x, u1.y, u1.z, u1.w};
        bf16x8 f;
        #pragma unroll
        for (int j = 0; j < 8; ++j) {
            float x = v[j] * SQRT_LOG2E;
            sq += x * x;
            f[j] = (bf16_t)x;
        }
        *(bf16x8*)(Xp + ((size_t)(g * 4 + i) * 64 + lane) * 8) = f;
    }
    sq += __shfl_xor(sq, 32);   // combine the two k-halves of the row
    if (half == 0) norms[row] = sq;
}

// Kernel 2: each block owns 32 rows of one batch; 8 waves, each wave owns a
// 32-col strip of a 256-col tile (16 tiles/pass). B-fragments for tile t+1
// are prefetched into registers before tile t's MFMA+epilogue (software
// pipeline) so L2 latency hides under compute. Plain stores (no NT): the
// packed panel is tiny (512 KB/batch), L2 eviction by the write stream is
// harmless, and plain stores match the fill's 6.4 TB/s write path.
__global__ __launch_bounds__(512, 4) void softmax_xxt_kernel(
        const bf16_t* __restrict__ Xp,
        const float* __restrict__ norms,
        float* __restrict__ Out) {
    const int tid  = threadIdx.x;
    const int wave = tid >> 6;                 // 0..7
    const int lane = tid & 63;
    const int b    = blockIdx.x >> 7;          // 128 row-strips per batch
    const int ga   = blockIdx.x & 127;         // row-group within batch
    const int rowbase = ga * 32;

    const bf16_t* Pb = Xp + (size_t)b * N_ * D_;   // packed panel for batch
    const int mcol = lane & 31;
    const int half = lane >> 5;

    // A fragments: packed group ga, frag i at + i*512 elements
    const bf16_t* ap = Pb + (size_t)ga * 2048 + (size_t)lane * 8;
    const bf16x8 a0 = *(const bf16x8*)(ap);
    const bf16x8 a1 = *(const bf16x8*)(ap + 512);
    const bf16x8 a2 = *(const bf16x8*)(ap + 1024);
    const bf16x8 a3 = *(const bf16x8*)(ap + 1536);

    // Stabilizer m2 (log2 domain) for the 16 rows this lane's acc regs map to:
    // row = (reg&3) + 8*(reg>>2) + 4*(lane>>5)   [measured m74/m101 C-layout]
    float lse[16];
    {
        const float* nb = norms + b * N_ + rowbase;
        #pragma unroll
        for (int r = 0; r < 16; ++r) {
            int row = (r & 3) + 8 * (r >> 2) + 4 * half;
            lse[r] = nb[row];
        }
    }

    __shared__ float partials[8][32];

    // ---------------- pass 1: denominators ----------------
    float sums[16];
    #pragma unroll
    for (int r = 0; r < 16; ++r) sums[r] = 0.0f;

    {
        const bf16_t* bp0 = Pb + (size_t)wave * 2048 + (size_t)lane * 8;
        bf16x8 nb0 = *(const bf16x8*)(bp0);
        bf16x8 nb1 = *(const bf16x8*)(bp0 + 512);
        bf16x8 nb2 = *(const bf16x8*)(bp0 + 1024);
        bf16x8 nb3 = *(const bf16x8*)(bp0 + 1536);
        for (int t = 0; t < N_ / 256; ++t) {
            bf16x8 b0 = nb0, b1 = nb1, b2 = nb2, b3 = nb3;
            if (t + 1 < N_ / 256) {
                const bf16_t* np = Pb + (size_t)((t + 1) * 8 + wave) * 2048
                                      + (size_t)lane * 8;
                nb0 = *(const bf16x8*)(np);
                nb1 = *(const bf16x8*)(np + 512);
                nb2 = *(const bf16x8*)(np + 1024);
                nb3 = *(const bf16x8*)(np + 1536);
            }
            f32x16 acc;
            #pragma unroll
            for (int i = 0; i < 16; ++i) acc[i] = 0.0f;
            acc = __builtin_amdgcn_mfma_f32_32x32x16_bf16(a0, b0, acc, 0, 0, 0);
            acc = __builtin_amdgcn_mfma_f32_32x32x16_bf16(a1, b1, acc, 0, 0, 0);
            acc = __builtin_amdgcn_mfma_f32_32x32x16_bf16(a2, b2, acc, 0, 0, 0);
            acc = __builtin_amdgcn_mfma_f32_32x32x16_bf16(a3, b3, acc, 0, 0, 0);
            #pragma unroll
            for (int r = 0; r < 16; ++r) sums[r] += EXP2F(acc[r] - lse[r]);
        }
    }

    // reduce over the 32 lanes (cols) of each half-wave
    #pragma unroll
    for (int r = 0; r < 16; ++r) {
        float s = sums[r];
        s += __shfl_xor(s, 1);
        s += __shfl_xor(s, 2);
        s += __shfl_xor(s, 4);
        s += __shfl_xor(s, 8);
        s += __shfl_xor(s, 16);
        sums[r] = s;
    }

    // cross-wave combine (each wave covered a different col span)
    if (mcol == 0) {
        #pragma unroll
        for (int r = 0; r < 16; ++r) {
            int row = (r & 3) + 8 * (r >> 2) + 4 * half;
            partials[wave][row] = sums[r];
        }
    }
    __syncthreads();

    #pragma unroll
    for (int r = 0; r < 16; ++r) {
        int row = (r & 3) + 8 * (r >> 2) + 4 * half;
        float tot = partials[0][row] + partials[1][row] +
                    partials[2][row] + partials[3][row] +
                    partials[4][row] + partials[5][row] +
                    partials[6][row] + partials[7][row];
        lse[r] += __log2f(tot);   // lse2 = m2 + log2(sum exp2(s2-m2))
    }

    // ---------------- pass 2: recompute + write ----------------
    float* outb = Out + (size_t)b * N_ * N_;
    {
        const bf16_t* bp0 = Pb + (size_t)wave * 2048 + (size_t)lane * 8;
        bf16x8 nb0 = *(const bf16x8*)(bp0);
        bf16x8 nb1 = *(const bf16x8*)(bp0 + 512);
        bf16x8 nb2 = *(const bf16x8*)(bp0 + 1024);
        bf16x8 nb3 = *(const bf16x8*)(bp0 + 1536);
        for (int t = 0; t < N_ / 256; ++t) {
            const int c0 = (t * 8 + wave) * 32;
            bf16x8 b0 = nb0, b1 = nb1, b2 = nb2, b3 = nb3;
            if (t + 1 < N_ / 256) {
                const bf16_t* np = Pb + (size_t)((t + 1) * 8 + wave) * 2048
                                      + (size_t)lane * 8;
                nb0 = *(const bf16x8*)(np);
                nb1 = *(const bf16x8*)(np + 512);
                nb2 = *(const bf16x8*)(np + 1024);
                nb3 = *(const bf16x8*)(np + 1536);
            }
            f32x16 acc;
            #pragma unroll
            for (int i = 0; i < 16; ++i) acc[i] = 0.0f;
            acc = __builtin_amdgcn_mfma_f32_32x32x16_bf16(a0, b0, acc, 0, 0, 0);
            acc = __builtin_amdgcn_mfma_f32_32x32x16_bf16(a1, b1, acc, 0, 0, 0);
            acc = __builtin_amdgcn_mfma_f32_32x32x16_bf16(a2, b2, acc, 0, 0, 0);
            acc = __builtin_amdgcn_mfma_f32_32x32x16_bf16(a3, b3, acc, 0, 0, 0);
            #pragma unroll
            for (int r = 0; r < 16; ++r) {
                int row = rowbase + (r & 3) + 8 * (r >> 2) + 4 * half;
                outb[(size_t)row * N_ + (c0 + mcol)] = EXP2F(acc[r] - lse[r]);
            }
        }
    }
}

extern "C" void kernel_launch(void* const* d_in, const int* in_sizes, int n_in,
                              void* d_out, int out_size, void* d_ws, size_t ws_size,
                              hipStream_t stream) {
    const float* X = (const float*)d_in[0];
    float* Out     = (float*)d_out;

    bf16_t* Xp    = (bf16_t*)d_ws;                                   // 2 MB packed
    float*  norms = (float*)((char*)d_ws + (size_t)B_ * N_ * D_ * sizeof(bf16_t)); // 64 KB

    conv_pack_kernel<<<(B_ * N_) / 128, 256, 0, stream>>>(X, Xp, norms);
    softmax_xxt_kernel<<<(B_ * N_) / 32, 512, 0, stream>>>(Xp, norms, Out);
}